// Round 2
// baseline (156.358 us; speedup 1.0000x reference)
//
#include <hip/hip_runtime.h>
#include <float.h>
#include <math.h>

#define NEG 0.2f

// ---------------- CSR build ----------------
__global__ void k_count(const int* __restrict__ ei, int E, int* deg) {
  int e = blockIdx.x * blockDim.x + threadIdx.x;
  if (e < E) atomicAdd(&deg[ei[E + e]], 1);
}

// one block, 1024 threads; each thread owns a contiguous range of nodes.
// On exit: offs/cursor = exclusive prefix of (deg+1); deg = deg+1 (self-loop).
__global__ __launch_bounds__(1024) void k_scan(int* deg, int* offs, int* cursor, int n) {
  __shared__ int wsum[16];
  int t = threadIdx.x;
  int ch = (n + 1023) >> 10;
  int lo = t * ch, hi = min(n, lo + ch);
  int s = 0;
  for (int i = lo; i < hi; i++) s += deg[i] + 1;
  int lane = t & 63, w = t >> 6;
  int v = s;
#pragma unroll
  for (int off = 1; off < 64; off <<= 1) {
    int o = __shfl_up(v, off);
    if (lane >= off) v += o;
  }
  if (lane == 63) wsum[w] = v;
  __syncthreads();
  if (t < 16) {
    int x = wsum[t];
#pragma unroll
    for (int off = 1; off < 16; off <<= 1) {
      int o = __shfl_up(x, off);
      if (t >= off) x += o;
    }
    wsum[t] = x;
  }
  __syncthreads();
  int excl = v - s + (w ? wsum[w - 1] : 0);
  for (int i = lo; i < hi; i++) {
    int d = deg[i] + 1;
    offs[i] = excl;
    cursor[i] = excl;
    deg[i] = d;
    excl += d;
  }
}

__global__ void k_scatter(const int* __restrict__ ei, int E, int N,
                          int* cursor, int* edge_src) {
  int t = blockIdx.x * blockDim.x + threadIdx.x;
  if (t < E) {
    int s = ei[t], d = ei[E + t];
    int pos = atomicAdd(&cursor[d], 1);
    edge_src[pos] = s;
  } else if (t < E + N) {
    int nn = t - E;
    int pos = atomicAdd(&cursor[nn], 1);
    edge_src[pos] = nn;
  }
}

// ---------------- layer-1 GEMM (h1 = x @ W1^T) + fused attention logits ----------------
// grid: (ceil(N/64), 8 heads); block 256.  col-tile == head (64 cols).
__global__ __launch_bounds__(256) void k_gemm1(
    const float* __restrict__ x, const float* __restrict__ W1,
    const float* __restrict__ a_s, const float* __restrict__ a_d,
    float* __restrict__ h1, float* __restrict__ as1, float* __restrict__ ad1, int N) {
  __shared__ float xs[64 * 129];
  __shared__ float wsl[64 * 129];
  int node0 = blockIdx.x * 64;
  int h = blockIdx.y;
  int col0 = h * 64;
  int tid = threadIdx.x;
  int nvalid = min(64, N - node0);

  const float4* x4 = (const float4*)x;
  const float4* w4 = (const float4*)W1;
#pragma unroll
  for (int i = 0; i < 8; i++) {
    int idx = tid + i * 256;
    int row = idx >> 5, kq = idx & 31;
    float4 v = make_float4(0.f, 0.f, 0.f, 0.f);
    if (row < nvalid) v = x4[(size_t)(node0 + row) * 32 + kq];
    float* p = &xs[row * 129 + kq * 4];
    p[0] = v.x; p[1] = v.y; p[2] = v.z; p[3] = v.w;
  }
#pragma unroll
  for (int i = 0; i < 8; i++) {
    int idx = tid + i * 256;
    int row = idx >> 5, kq = idx & 31;
    float4 v = w4[(size_t)(col0 + row) * 32 + kq];
    float* p = &wsl[row * 129 + kq * 4];
    p[0] = v.x; p[1] = v.y; p[2] = v.z; p[3] = v.w;
  }
  __syncthreads();

  int tx = tid & 15, ty = tid >> 4;
  float acc[4][4] = {};
  for (int k = 0; k < 128; k++) {
    float a[4], b[4];
#pragma unroll
    for (int i = 0; i < 4; i++) a[i] = xs[(ty * 4 + i) * 129 + k];
#pragma unroll
    for (int j = 0; j < 4; j++) b[j] = wsl[(tx * 4 + j) * 129 + k];
#pragma unroll
    for (int i = 0; i < 4; i++)
#pragma unroll
      for (int j = 0; j < 4; j++) acc[i][j] = fmaf(a[i], b[j], acc[i][j]);
  }

#pragma unroll
  for (int i = 0; i < 4; i++) {
    int node = node0 + ty * 4 + i;
    if (node < N) {
      float4 v = make_float4(acc[i][0], acc[i][1], acc[i][2], acc[i][3]);
      *(float4*)&h1[(size_t)node * 512 + col0 + tx * 4] = v;
    }
  }
  float ps[4], pd[4];
#pragma unroll
  for (int i = 0; i < 4; i++) {
    float s = 0.f, d = 0.f;
#pragma unroll
    for (int j = 0; j < 4; j++) {
      float av = a_s[h * 64 + tx * 4 + j];
      float dv = a_d[h * 64 + tx * 4 + j];
      s = fmaf(acc[i][j], av, s);
      d = fmaf(acc[i][j], dv, d);
    }
    ps[i] = s; pd[i] = d;
  }
#pragma unroll
  for (int o = 8; o >= 1; o >>= 1) {
#pragma unroll
    for (int i = 0; i < 4; i++) {
      ps[i] += __shfl_xor(ps[i], o);
      pd[i] += __shfl_xor(pd[i], o);
    }
  }
  if (tx == 0) {
#pragma unroll
    for (int i = 0; i < 4; i++) {
      int node = node0 + ty * 4 + i;
      if (node < N) { as1[node * 8 + h] = ps[i]; ad1[node * 8 + h] = pd[i]; }
    }
  }
}

// ---------------- layer-1 aggregation: ONE WAVE PER NODE, no LDS, no barriers ---------
// lane-space for logits: (j, h) = (lane>>3, lane&7) -> 8 edges x 8 heads per step.
// aggregation: lane owns channels [lane*8, lane*8+8) (head = lane>>3).
// epilogue fuses bias + ELU + layer-2 linear + layer-2 logits.
__global__ __launch_bounds__(256) void k_gat1(
    const float* __restrict__ h1, const float* __restrict__ as1, const float* __restrict__ ad1,
    const int* __restrict__ offs, const int* __restrict__ degs, const int* __restrict__ edge_src,
    const float* __restrict__ b1, const float* __restrict__ W2,
    const float* __restrict__ a_s2, const float* __restrict__ a_d2,
    float* __restrict__ h2, float* __restrict__ as2, float* __restrict__ ad2, int N) {
  int lane = threadIdx.x & 63;
  int n = blockIdx.x * 4 + (threadIdx.x >> 6);
  if (n >= N) return;
  int start = offs[n], dg = degs[n];
  int hh = lane & 7;
  int jj0 = lane >> 3;
  float adv = ad1[n * 8 + hh];

  // pass A: per-head max of leaky_relu logits
  float m = -FLT_MAX;
  for (int base = 0; base < dg; base += 8) {
    int j = base + jj0;
    if (j < dg) {
      int s = edge_src[start + j];
      float v = as1[s * 8 + hh] + adv;
      v = v > 0.f ? v : NEG * v;
      m = fmaxf(m, v);
    }
  }
  m = fmaxf(m, __shfl_xor(m, 8));
  m = fmaxf(m, __shfl_xor(m, 16));
  m = fmaxf(m, __shfl_xor(m, 32));

  // pass B: exp weights + denominator + weighted aggregation
  float den = 0.f;
  float acc[8] = {};
  const float4* h14 = (const float4*)h1;
  int myh = lane >> 3;  // head of my channels
  for (int base = 0; base < dg; base += 8) {
    int j = base + jj0;
    float w = 0.f;
    int s = 0;
    if (j < dg) {
      s = edge_src[start + j];
      float v = as1[s * 8 + hh] + adv;
      v = v > 0.f ? v : NEG * v;
      w = expf(v - m);
      den += w;
    }
    int cnt = min(8, dg - base);
    for (int q = 0; q < cnt; q++) {
      float wq = __shfl(w, q * 8 + myh);
      int sq = __shfl(s, q * 8);
      float4 v0 = h14[(size_t)sq * 128 + lane * 2];
      float4 v1 = h14[(size_t)sq * 128 + lane * 2 + 1];
      acc[0] = fmaf(wq, v0.x, acc[0]);
      acc[1] = fmaf(wq, v0.y, acc[1]);
      acc[2] = fmaf(wq, v0.z, acc[2]);
      acc[3] = fmaf(wq, v0.w, acc[3]);
      acc[4] = fmaf(wq, v1.x, acc[4]);
      acc[5] = fmaf(wq, v1.y, acc[5]);
      acc[6] = fmaf(wq, v1.z, acc[6]);
      acc[7] = fmaf(wq, v1.w, acc[7]);
    }
  }
  den += __shfl_xor(den, 8);
  den += __shfl_xor(den, 16);
  den += __shfl_xor(den, 32);
  float dn = __shfl(den, myh) + 1e-16f;  // lane myh holds head-myh denom

  // epilogue: bias + ELU + fused layer-2 linear (W2: [2][512]) + layer-2 logits
  float p0 = 0.f, p1 = 0.f;
  int c0 = lane * 8;
#pragma unroll
  for (int c = 0; c < 8; c++) {
    float v = acc[c] / dn + b1[c0 + c];
    v = v > 0.f ? v : expm1f(v);
    p0 = fmaf(v, W2[c0 + c], p0);
    p1 = fmaf(v, W2[512 + c0 + c], p1);
  }
#pragma unroll
  for (int o = 1; o < 64; o <<= 1) {
    p0 += __shfl_xor(p0, o);
    p1 += __shfl_xor(p1, o);
  }
  if (lane == 0) {
    ((float2*)h2)[n] = make_float2(p0, p1);
    as2[n] = p0 * a_s2[0] + p1 * a_s2[1];
    ad2[n] = p0 * a_d2[0] + p1 * a_d2[1];
  }
}

// ---------------- layer-2 aggregation: one wave per node, 4 waves/block ----------------
__global__ __launch_bounds__(256) void k_gat2(
    const float* __restrict__ h2, const float* __restrict__ as2, const float* __restrict__ ad2,
    const int* __restrict__ offs, const int* __restrict__ degs, const int* __restrict__ edge_src,
    const float* __restrict__ b2, float* __restrict__ out, int N) {
  int lane = threadIdx.x & 63;
  int n = blockIdx.x * 4 + (threadIdx.x >> 6);
  if (n >= N) return;
  int start = offs[n], dg = degs[n];
  float adn = ad2[n];
  float m = -FLT_MAX;
  for (int j = lane; j < dg; j += 64) {
    int s = edge_src[start + j];
    float v = as2[s] + adn;
    v = v > 0.f ? v : NEG * v;
    m = fmaxf(m, v);
  }
#pragma unroll
  for (int o = 32; o >= 1; o >>= 1) m = fmaxf(m, __shfl_xor(m, o));
  float den = 0.f, n0 = 0.f, n1 = 0.f;
  const float2* h2f = (const float2*)h2;
  for (int j = lane; j < dg; j += 64) {
    int s = edge_src[start + j];
    float v = as2[s] + adn;
    v = v > 0.f ? v : NEG * v;
    float w = expf(v - m);
    float2 hv = h2f[s];
    den += w;
    n0 = fmaf(w, hv.x, n0);
    n1 = fmaf(w, hv.y, n1);
  }
#pragma unroll
  for (int o = 32; o >= 1; o >>= 1) {
    den += __shfl_xor(den, o);
    n0 += __shfl_xor(n0, o);
    n1 += __shfl_xor(n1, o);
  }
  if (lane == 0) {
    out[n * 2 + 0] = n0 / (den + 1e-16f) + b2[0];
    out[n * 2 + 1] = n1 / (den + 1e-16f) + b2[1];
  }
}

extern "C" void kernel_launch(void* const* d_in, const int* in_sizes, int n_in,
                              void* d_out, int out_size, void* d_ws, size_t ws_size,
                              hipStream_t stream) {
  const float* x    = (const float*)d_in[0];
  const int*   ei   = (const int*)d_in[1];
  const float* W1   = (const float*)d_in[2];
  const float* a_s1 = (const float*)d_in[3];
  const float* a_d1 = (const float*)d_in[4];
  const float* b1   = (const float*)d_in[5];
  const float* W2   = (const float*)d_in[6];
  const float* a_s2 = (const float*)d_in[7];
  const float* a_d2 = (const float*)d_in[8];
  const float* b2   = (const float*)d_in[9];
  int N = in_sizes[0] / 128;
  int E = in_sizes[1] / 2;

  float* ws  = (float*)d_ws;
  float* h1  = ws;                              // N*512
  float* as1 = h1 + (size_t)N * 512;            // N*8
  float* ad1 = as1 + (size_t)N * 8;             // N*8
  float* h2  = ad1 + (size_t)N * 8;             // N*2
  float* as2 = h2 + (size_t)N * 2;              // N
  float* ad2 = as2 + N;                         // N
  int* deg      = (int*)(ad2 + N);              // N
  int* offs     = deg + N;                      // N
  int* cursor   = offs + N;                     // N
  int* edge_src = cursor + N;                   // E+N

  hipMemsetAsync(deg, 0, (size_t)N * sizeof(int), stream);
  k_count<<<(E + 255) / 256, 256, 0, stream>>>(ei, E, deg);
  k_scan<<<1, 1024, 0, stream>>>(deg, offs, cursor, N);
  k_scatter<<<(E + N + 255) / 256, 256, 0, stream>>>(ei, E, N, cursor, edge_src);
  dim3 g1((N + 63) / 64, 8);
  k_gemm1<<<g1, 256, 0, stream>>>(x, W1, a_s1, a_d1, h1, as1, ad1, N);
  k_gat1<<<(N + 3) / 4, 256, 0, stream>>>(h1, as1, ad1, offs, deg, edge_src, b1, W2,
                                          a_s2, a_d2, h2, as2, ad2, N);
  k_gat2<<<(N + 3) / 4, 256, 0, stream>>>(h2, as2, ad2, offs, deg, edge_src, b2,
                                          (float*)d_out, N);
}